// Round 10
// baseline (422.672 us; speedup 1.0000x reference)
//
#include <hip/hip_runtime.h>
#include <hip/hip_fp16.h>
#include <hip/hip_fp8.h>
#include <stdint.h>

#define U_N 100000
#define I_N 50000
#define D_DIM 64
#define E_N 6400000
#define B_N 16384
#define N_N 150000
#define BKN 128            // nodes per bucket (power of 2: bucket = dst>>7)
#define NB 1172            // ceil(150000/128)
#define CAPB 6144          // per-bucket slot capacity (lambda=5461, +9 sigma)
#define CHUNK_A 5000       // edges per phaseA block (1280 blocks exactly; LDS 49.4KB -> 3 blocks/CU)
#define PAIRS 586          // NB/2

#define S1_F 1024.0f       // fp8 scale for layer-1 output table (e1 ~ 0.012 rms)
#define S2_F 8192.0f       // fp8 scale for layer-2 output table (e2 ~ 0.0014 rms)

typedef unsigned long long ull;
typedef __attribute__((ext_vector_type(2))) float f32x2;

// ---------- fp8 e4m3 pack/unpack (HW cvt with header-type fallback) ----------
__device__ __forceinline__ unsigned short pack_fp8(float a, float b) {
#if __has_builtin(__builtin_amdgcn_cvt_pk_fp8_f32)
    return (unsigned short)(__builtin_amdgcn_cvt_pk_fp8_f32(a, b, 0, false) & 0xFFFF);
#else
    __hip_fp8_e4m3 qa(a), qb(b);
    return (unsigned short)((unsigned)qa.__x | ((unsigned)qb.__x << 8));
#endif
}
__device__ __forceinline__ f32x2 unpack_fp8(unsigned short u) {
#if __has_builtin(__builtin_amdgcn_cvt_pk_f32_fp8)
    return __builtin_amdgcn_cvt_pk_f32_fp8((int)(unsigned)u, false);
#else
    __hip_fp8_e4m3 qa, qb;
    qa.__x = (unsigned char)(u & 0xFF);
    qb.__x = (unsigned char)(u >> 8);
    f32x2 r; r[0] = (float)qa; r[1] = (float)qb; return r;
#endif
}

// ---------- convert concat(user_emb,item_emb) -> fp16 table ----------
__global__ __launch_bounds__(256) void to_half(const float2* __restrict__ ue,
                                               const float2* __restrict__ ie,
                                               __half2* __restrict__ h) {
    const int n2 = N_N * D_DIM / 2;
    const int u2 = U_N * D_DIM / 2;
    for (int i = blockIdx.x * blockDim.x + threadIdx.x; i < n2;
         i += gridDim.x * blockDim.x) {
        float2 x = (i < u2) ? ue[i] : ie[i - u2];
        h[i] = __floats2half2_rn(x.x, x.y);
    }
}

// ---------- phase A: per-block counting sort into LDS, coalesced sweep out ----------
// record (52 bits): val_fp16<<36 | dst18<<18 | src18
__global__ __launch_bounds__(1024) void phaseA(const int* __restrict__ src,
                                               const int* __restrict__ dst,
                                               const float* __restrict__ vals,
                                               int* __restrict__ bcur,
                                               ull* __restrict__ staging) {
    __shared__ int hist[NB];     // counts -> excl bases -> running cursors
    __shared__ int delta[NB];    // global_pos = delta[b] + lds_index
    __shared__ ull recs[CHUNK_A];
    __shared__ int wsum[10];
    const int tid = threadIdx.x;
    const int beg = blockIdx.x * CHUNK_A;

    for (int i = tid; i < NB; i += 1024) hist[i] = 0;
    __syncthreads();
    // pass 1: bucket histogram
    for (int e = tid; e < CHUNK_A; e += 1024)
        atomicAdd(&hist[((unsigned)dst[beg + e]) >> 7], 1);
    __syncthreads();

    // exclusive scan of hist[NB]: 2 entries per thread, wave scan + wave-total scan
    int e0 = 0, e1 = 0, s = 0;
    if (tid < PAIRS) { e0 = hist[2 * tid]; e1 = hist[2 * tid + 1]; s = e0 + e1; }
    int incl = s;
#pragma unroll
    for (int off = 1; off < 64; off <<= 1) {
        int v = __shfl_up(incl, off, 64);
        if ((tid & 63) >= off) incl += v;
    }
    if ((tid & 63) == 63 && (tid >> 6) < 10) wsum[tid >> 6] = incl;
    __syncthreads();
    if (tid == 0) {
        int run = 0;
        for (int w = 0; w < 10; ++w) { int t = wsum[w]; wsum[w] = run; run += t; }
    }
    __syncthreads();
    if (tid < PAIRS) {
        int excl = wsum[tid >> 6] + incl - s;       // base of bucket 2*tid
        int b0 = 2 * tid, b1 = 2 * tid + 1;
        int g0 = e0 ? atomicAdd(&bcur[b0], e0) : 0; // reserve global slots
        int g1 = e1 ? atomicAdd(&bcur[b1], e1) : 0;
        delta[b0] = b0 * CAPB + g0 - excl;
        delta[b1] = b1 * CAPB + g1 - (excl + e0);
        hist[b0] = excl;                            // cursor init
        hist[b1] = excl + e0;
    }
    __syncthreads();

    // pass 2: scatter records into LDS, sorted by bucket
    for (int e = tid; e < CHUNK_A; e += 1024) {
        int d = dst[beg + e];
        unsigned b = ((unsigned)d) >> 7;
        unsigned short hb = __half_as_ushort(__float2half(vals[beg + e]));
        ull rec = ((ull)hb << 36) | ((ull)(unsigned)d << 18)
                | (ull)(unsigned)src[beg + e];
        int lpos = atomicAdd(&hist[b], 1);
        recs[lpos] = rec;
    }
    __syncthreads();

    // sweep: consecutive lanes -> consecutive global addrs within bucket runs
    for (int i = tid; i < CHUNK_A; i += 1024) {
        ull rec = recs[i];
        unsigned d = (unsigned)(rec >> 18) & 0x3FFFFu;
        unsigned b = d >> 7;
        staging[(size_t)(delta[b] + i)] = rec;
    }
}

// ---------- phase B: one block per bucket; sort by node, emit split CSR ----------
// No LDS record cache: staging re-read hits L2/L3. 1KB LDS -> high occupancy.
// csr_src holds BYTE offsets into the fp16 table (src * 128)
__global__ __launch_bounds__(256) void phaseB(const ull* __restrict__ staging,
                                              const int* __restrict__ bcur,
                                              unsigned* __restrict__ csr_src,
                                              __half* __restrict__ csr_val,
                                              int* __restrict__ row_ptr,
                                              unsigned short* __restrict__ row_len) {
    __shared__ int hist[BKN];
    __shared__ int curs[BKN];
    const int b = blockIdx.x;
    const int cnt = bcur[b];
    const int sbase = b * CAPB;
    for (int i = threadIdx.x; i < BKN; i += 256) hist[i] = 0;
    __syncthreads();
    for (int i = threadIdx.x; i < cnt; i += 256) {
        ull rec = staging[sbase + i];
        atomicAdd(&hist[(int)((rec >> 18) & 0x7Fu)], 1);
    }
    __syncthreads();
    // wave 0: exclusive scan of 128 counts; write row_ptr/row_len + cursors
    if (threadIdx.x < 64) {
        int lane = threadIdx.x;
        int carry = 0;
#pragma unroll
        for (int c = 0; c < BKN; c += 64) {
            int x = hist[c + lane];
            int inc = x;
#pragma unroll
            for (int off = 1; off < 64; off <<= 1) {
                int v = __shfl_up(inc, off, 64);
                if (lane >= off) inc += v;
            }
            int excl = carry + inc - x;
            int node = b * BKN + c + lane;
            if (node < N_N) {
                row_ptr[node] = sbase + excl;
                row_len[node] = (unsigned short)x;
            }
            curs[c + lane] = excl;
            carry += __shfl(inc, 63, 64);
        }
    }
    __syncthreads();
    for (int i = threadIdx.x; i < cnt; i += 256) {
        ull rec = staging[sbase + i];          // L2-hot re-read
        int local = (int)((rec >> 18) & 0x7Fu);
        int pos = sbase + atomicAdd(&curs[local], 1);
        csr_src[pos] = (unsigned)((rec & 0x3FFFFu) << 7);   // byte offset (fp16)
        csr_val[pos] = __ushort_as_half((unsigned short)(rec >> 36));
    }
}

// ---------- fp16-gather inner loop (2 edges/instr, LDS record broadcast) ----------
__device__ __forceinline__ void spmm_row(const char* __restrict__ eb,
                                         const unsigned* __restrict__ csr_src,
                                         const __half* __restrict__ csr_val,
                                         int2 (*recs)[64], int wid, int lane,
                                         int hlf, int col4,
                                         int beg, int end,
                                         float& accx, float& accy) {
    for (int base = beg; base < end; base += 64) {
        int2 rec;
        if (base + lane < end) {
            rec.x = (int)csr_src[base + lane];
            rec.y = __float_as_int(__half2float(csr_val[base + lane]));
        } else {
            rec = make_int2(0, 0);
        }
        recs[wid][lane] = rec;
        int cnt = min(64, end - base);
        int j0 = 0;
        for (; j0 + 32 <= cnt; j0 += 32) {
            unsigned g[16];
            float v[16];
#pragma unroll
            for (int k = 0; k < 16; ++k) {
                int2 r = recs[wid][j0 + 2 * k + hlf];
                v[k] = __int_as_float(r.y);
                g[k] = *(const unsigned*)(eb + (size_t)(unsigned)r.x + col4);
            }
#pragma unroll
            for (int k = 0; k < 16; ++k) {
                __half2 h = *(__half2*)&g[k];
                accx += __low2float(h) * v[k];
                accy += __high2float(h) * v[k];
            }
        }
        for (; j0 < cnt; j0 += 16) {
            unsigned g[8];
            float v[8];
#pragma unroll
            for (int k = 0; k < 8; ++k) {
                int2 r = recs[wid][j0 + 2 * k + hlf];
                v[k] = __int_as_float(r.y);
                g[k] = *(const unsigned*)(eb + (size_t)(unsigned)r.x + col4);
            }
#pragma unroll
            for (int k = 0; k < 8; ++k) {
                __half2 h = *(__half2*)&g[k];
                accx += __low2float(h) * v[k];
                accy += __high2float(h) * v[k];
            }
        }
    }
}

// ---------- fp8-gather inner loop ----------
template<int M>
__device__ __forceinline__ void gather_fma8(const char* __restrict__ eb8,
                                            int2 (*recs)[64], int wid, int j0,
                                            int hlf, int col2,
                                            float& accx, float& accy) {
    unsigned short g[M];
    float v[M];
#pragma unroll
    for (int k = 0; k < M; ++k) {
        int2 r = recs[wid][j0 + 2 * k + hlf];
        v[k] = __int_as_float(r.y);
        g[k] = *(const unsigned short*)(eb8 + (size_t)((unsigned)r.x >> 1) + col2);
    }
#pragma unroll
    for (int k = 0; k < M; ++k) {
        f32x2 f = unpack_fp8(g[k]);
        accx += f[0] * v[k];
        accy += f[1] * v[k];
    }
}

__device__ __forceinline__ void spmm_row8(const char* __restrict__ eb8,
                                          const unsigned* __restrict__ csr_src,
                                          const __half* __restrict__ csr_val,
                                          int2 (*recs)[64], int wid, int lane,
                                          int hlf, int col2,
                                          int beg, int end,
                                          float& accx, float& accy) {
    for (int base = beg; base < end; base += 64) {
        int2 rec;
        if (base + lane < end) {
            rec.x = (int)csr_src[base + lane];
            rec.y = __float_as_int(__half2float(csr_val[base + lane]));
        } else {
            rec = make_int2(0, 0);
        }
        recs[wid][lane] = rec;
        int cnt = min(64, end - base);
        int j0 = 0;
        for (; j0 + 32 <= cnt; j0 += 32)
            gather_fma8<16>(eb8, recs, wid, j0, hlf, col2, accx, accy);
        for (; j0 < cnt; j0 += 16)
            gather_fma8<8>(eb8, recs, wid, j0, hlf, col2, accx, accy);
    }
}

// ---------- layer 1: fp16 gathers; writes fp16 table + scaled fp8 table ----------
__global__ __launch_bounds__(256) void spmm16(const __half2* __restrict__ ecur,
                                              __half2* __restrict__ enext,
                                              unsigned short* __restrict__ out8,
                                              const int* __restrict__ row_ptr,
                                              const unsigned short* __restrict__ row_len,
                                              const unsigned* __restrict__ csr_src,
                                              const __half* __restrict__ csr_val) {
    __shared__ int2 recs[4][64];
    const int wid = threadIdx.x >> 6;
    const int lane = threadIdx.x & 63;
    const int hlf = lane >> 5;
    const int col = lane & 31;
    int row = blockIdx.x * 4 + wid;
    if (row >= N_N) return;
    int beg = row_ptr[row];
    int end = beg + row_len[row];
    float accx = 0.f, accy = 0.f;
    spmm_row((const char*)ecur, csr_src, csr_val, recs, wid, lane, hlf,
             col * 4, beg, end, accx, accy);
    accx += __shfl_xor(accx, 32, 64);
    accy += __shfl_xor(accy, 32, 64);
    if (lane < 32) {
        enext[(size_t)row * 32 + col] = __floats2half2_rn(accx, accy);
        out8[(size_t)row * 32 + col] = pack_fp8(accx * S1_F, accy * S1_F);
    }
}

// ---------- layer 2: fp8 gathers (S1-scaled); writes fp16 (/S1) + fp8 (*S2/S1) ----------
__global__ __launch_bounds__(256) void spmm8(const unsigned short* __restrict__ e8,
                                             __half2* __restrict__ enext,
                                             unsigned short* __restrict__ out8,
                                             const int* __restrict__ row_ptr,
                                             const unsigned short* __restrict__ row_len,
                                             const unsigned* __restrict__ csr_src,
                                             const __half* __restrict__ csr_val) {
    __shared__ int2 recs[4][64];
    const int wid = threadIdx.x >> 6;
    const int lane = threadIdx.x & 63;
    const int hlf = lane >> 5;
    const int col = lane & 31;
    int row = blockIdx.x * 4 + wid;
    if (row >= N_N) return;
    int beg = row_ptr[row];
    int end = beg + row_len[row];
    float accx = 0.f, accy = 0.f;
    spmm_row8((const char*)e8, csr_src, csr_val, recs, wid, lane, hlf,
              col * 2, beg, end, accx, accy);
    accx += __shfl_xor(accx, 32, 64);
    accy += __shfl_xor(accy, 32, 64);
    if (lane < 32) {
        enext[(size_t)row * 32 + col] =
            __floats2half2_rn(accx * (1.0f / S1_F), accy * (1.0f / S1_F));
        out8[(size_t)row * 32 + col] =
            pack_fp8(accx * (S2_F / S1_F), accy * (S2_F / S1_F));
    }
}

// ---------- layer 3: fp8 gathers (S2-scaled), only sampled rows, f32 accum ----------
__global__ __launch_bounds__(256) void spmm8_batch(const unsigned short* __restrict__ e8,
                                                   const int* __restrict__ users,
                                                   const int* __restrict__ items,
                                                   const int* __restrict__ row_ptr,
                                                   const unsigned short* __restrict__ row_len,
                                                   const unsigned* __restrict__ csr_src,
                                                   const __half* __restrict__ csr_val,
                                                   float2* __restrict__ su2,
                                                   float2* __restrict__ si2) {
    __shared__ int2 recs[4][64];
    const int wid = threadIdx.x >> 6;
    const int lane = threadIdx.x & 63;
    const int hlf = lane >> 5;
    const int col = lane & 31;
    int r = blockIdx.x * 4 + wid;
    if (r >= 2 * B_N) return;
    int node = (r < B_N) ? users[r] : U_N + items[r - B_N];
    int beg = row_ptr[node];
    int end = beg + row_len[node];
    float accx = 0.f, accy = 0.f;
    spmm_row8((const char*)e8, csr_src, csr_val, recs, wid, lane, hlf,
              col * 2, beg, end, accx, accy);
    accx += __shfl_xor(accx, 32, 64);
    accy += __shfl_xor(accy, 32, 64);
    if (lane < 32) {
        float2* o = (r < B_N) ? (su2 + (size_t)r * 32 + col)
                              : (si2 + (size_t)(r - B_N) * 32 + col);
        float2 t = *o;
        t.x += accx * (1.0f / S2_F);
        t.y += accy * (1.0f / S2_F);
        *o = t;
    }
}

// ---------- layer-0 accumulate from fp32 originals ----------
__global__ __launch_bounds__(256) void accum_f32(const float* __restrict__ ue,
                                                 const float* __restrict__ ie,
                                                 const int* __restrict__ users,
                                                 const int* __restrict__ items,
                                                 float* __restrict__ su,
                                                 float* __restrict__ si) {
    int r = blockIdx.x * 4 + (threadIdx.x >> 6);
    int lane = threadIdx.x & 63;
    if (r >= 2 * B_N) return;
    if (r < B_N) {
        su[(size_t)r * D_DIM + lane] += ue[(size_t)users[r] * D_DIM + lane];
    } else {
        int q = r - B_N;
        si[(size_t)q * D_DIM + lane] += ie[(size_t)items[q] * D_DIM + lane];
    }
}

// ---------- layer accumulate from fp16 table ----------
__global__ __launch_bounds__(256) void accum_h16(const __half* __restrict__ emb,
                                                 const int* __restrict__ users,
                                                 const int* __restrict__ items,
                                                 float* __restrict__ su,
                                                 float* __restrict__ si) {
    int r = blockIdx.x * 4 + (threadIdx.x >> 6);
    int lane = threadIdx.x & 63;
    if (r >= 2 * B_N) return;
    if (r < B_N) {
        su[(size_t)r * D_DIM + lane] +=
            __half2float(emb[(size_t)users[r] * D_DIM + lane]);
    } else {
        int q = r - B_N;
        si[(size_t)q * D_DIM + lane] +=
            __half2float(emb[((size_t)U_N + items[q]) * D_DIM + lane]);
    }
}

// ---------- gamma = su.si/16 + 64*(ub+ib) ----------
__global__ __launch_bounds__(256) void gamma_kernel(const float* __restrict__ su,
                                                    const float* __restrict__ si,
                                                    const float* __restrict__ ub,
                                                    const float* __restrict__ ib,
                                                    const int* __restrict__ users,
                                                    const int* __restrict__ items,
                                                    float* __restrict__ out) {
    int b = blockIdx.x * 4 + (threadIdx.x >> 6);
    int lane = threadIdx.x & 63;
    if (b >= B_N) return;
    float p = su[(size_t)b * D_DIM + lane] * si[(size_t)b * D_DIM + lane];
#pragma unroll
    for (int off = 32; off > 0; off >>= 1) p += __shfl_xor(p, off, 64);
    if (lane == 0) {
        float bias = ub[users[b]] + ib[items[b]];
        out[b] = p * (1.0f / 16.0f) + 64.0f * bias;
    }
}

extern "C" void kernel_launch(void* const* d_in, const int* in_sizes, int n_in,
                              void* d_out, int out_size, void* d_ws, size_t ws_size,
                              hipStream_t stream) {
    const float* user_emb  = (const float*)d_in[0];
    const float* item_emb  = (const float*)d_in[1];
    const float* user_bias = (const float*)d_in[2];
    const float* item_bias = (const float*)d_in[3];
    const float* vals      = (const float*)d_in[4];
    const int*   src       = (const int*)d_in[5];
    const int*   dst       = (const int*)d_in[6];
    const int*   users     = (const int*)d_in[7];
    const int*   items     = (const int*)d_in[8];
    float* out = (float*)d_out;

    char* ws = (char*)d_ws;
    size_t off = 0;
    auto alloc = [&](size_t bytes) -> void* {
        void* p = ws + off;
        off += (bytes + 255) & ~(size_t)255;
        return p;
    };
    const size_t SLOTS = (size_t)NB * CAPB;                                   // 7.2M
    __half* hA      = (__half*)alloc(sizeof(__half) * (size_t)N_N * D_DIM);   // 19.2MB
    __half* hB      = (__half*)alloc(sizeof(__half) * (size_t)N_N * D_DIM);   // 19.2MB
    unsigned short* b81 = (unsigned short*)alloc(sizeof(short) * (size_t)N_N * 32); // 9.6MB
    unsigned short* b82 = (unsigned short*)alloc(sizeof(short) * (size_t)N_N * 32); // 9.6MB
    float*  su      = (float*)alloc(sizeof(float) * (size_t)B_N * D_DIM);     // 4.2MB
    float*  si      = (float*)alloc(sizeof(float) * (size_t)B_N * D_DIM);     // 4.2MB
    int*    row_ptr = (int*)alloc(sizeof(int) * N_N);                         // 0.6MB
    unsigned short* row_len = (unsigned short*)alloc(sizeof(short) * N_N);    // 0.3MB
    int*    bcur    = (int*)alloc(sizeof(int) * NB);
    ull*    staging = (ull*)alloc(sizeof(ull) * SLOTS);                       // 57.6MB
    unsigned* csr_src = (unsigned*)alloc(sizeof(unsigned) * SLOTS);           // 28.8MB
    __half* csr_val = (__half*)alloc(sizeof(__half) * SLOTS);                 // 14.4MB

    hipMemsetAsync(su, 0, sizeof(float) * (size_t)B_N * D_DIM * 2, stream);
    hipMemsetAsync(bcur, 0, sizeof(int) * NB, stream);

    to_half<<<2048, 256, 0, stream>>>((const float2*)user_emb,
                                      (const float2*)item_emb, (__half2*)hA);
    phaseA<<<1280, 1024, 0, stream>>>(src, dst, vals, bcur, staging);
    phaseB<<<NB, 256, 0, stream>>>(staging, bcur, csr_src, csr_val,
                                   row_ptr, row_len);

    // layer 0 contribution from fp32 originals
    accum_f32<<<(2 * B_N) / 4, 256, 0, stream>>>(user_emb, item_emb, users,
                                                 items, su, si);
    // layer 1: fp16 gathers from hA; write hB (fp16) + b81 (fp8 * S1)
    spmm16<<<(N_N + 3) / 4, 256, 0, stream>>>((const __half2*)hA, (__half2*)hB, b81,
                                              row_ptr, row_len, csr_src, csr_val);
    accum_h16<<<(2 * B_N) / 4, 256, 0, stream>>>(hB, users, items, su, si);
    // layer 2: fp8 gathers from b81; write hA (fp16) + b82 (fp8 * S2)
    spmm8<<<(N_N + 3) / 4, 256, 0, stream>>>(b81, (__half2*)hA, b82,
                                             row_ptr, row_len, csr_src, csr_val);
    accum_h16<<<(2 * B_N) / 4, 256, 0, stream>>>(hA, users, items, su, si);
    // layer 3: fp8 gathers from b82, only sampled rows, straight into su/si
    spmm8_batch<<<(2 * B_N) / 4, 256, 0, stream>>>(b82, users, items,
                                                   row_ptr, row_len, csr_src, csr_val,
                                                   (float2*)su, (float2*)si);

    gamma_kernel<<<B_N / 4, 256, 0, stream>>>(su, si, user_bias, item_bias,
                                              users, items, out);
}

// Round 11
// 369.604 us; speedup vs baseline: 1.1436x; 1.1436x over previous
//
#include <hip/hip_runtime.h>
#include <hip/hip_fp16.h>
#include <hip/hip_fp8.h>
#include <stdint.h>

#define U_N 100000
#define I_N 50000
#define D_DIM 64
#define E_N 6400000
#define B_N 16384
#define N_N 150000
#define BKN 128            // nodes per bucket (power of 2: bucket = dst>>7)
#define NB 1172            // ceil(150000/128)
#define CAPB 6144          // per-bucket slot capacity (lambda=5461, +9 sigma)
#define CHUNK_A 6250       // edges per phaseA block (1024 blocks exactly)
#define PAIRS 586          // NB/2

#define S1_F 1024.0f       // fp8 scale for e1 table
#define S2_F 8192.0f       // fp8 scale for e2 table

typedef unsigned long long ull;
typedef __attribute__((ext_vector_type(2))) float f32x2;

// ---------- fp8 e4m3 pack/unpack (HW cvt with header-type fallback) ----------
__device__ __forceinline__ unsigned short pack_fp8(float a, float b) {
#if __has_builtin(__builtin_amdgcn_cvt_pk_fp8_f32)
    return (unsigned short)(__builtin_amdgcn_cvt_pk_fp8_f32(a, b, 0, false) & 0xFFFF);
#else
    __hip_fp8_e4m3 qa(a), qb(b);
    return (unsigned short)((unsigned)qa.__x | ((unsigned)qb.__x << 8));
#endif
}
__device__ __forceinline__ f32x2 unpack_fp8(unsigned short u) {
#if __has_builtin(__builtin_amdgcn_cvt_pk_f32_fp8)
    return __builtin_amdgcn_cvt_pk_f32_fp8((int)(unsigned)u, false);
#else
    __hip_fp8_e4m3 qa, qb;
    qa.__x = (unsigned char)(u & 0xFF);
    qb.__x = (unsigned char)(u >> 8);
    f32x2 r; r[0] = (float)qa; r[1] = (float)qb; return r;
#endif
}

// ---------- convert concat(user_emb,item_emb) -> fp16 table h0 ----------
__global__ __launch_bounds__(256) void to_half(const float2* __restrict__ ue,
                                               const float2* __restrict__ ie,
                                               __half2* __restrict__ h) {
    const int n2 = N_N * D_DIM / 2;
    const int u2 = U_N * D_DIM / 2;
    for (int i = blockIdx.x * blockDim.x + threadIdx.x; i < n2;
         i += gridDim.x * blockDim.x) {
        float2 x = (i < u2) ? ue[i] : ie[i - u2];
        h[i] = __floats2half2_rn(x.x, x.y);
    }
}

// ---------- phase A: per-block counting sort into LDS, coalesced sweep out ----------
// record (52 bits): val_fp16<<36 | dst18<<18 | src18
__global__ __launch_bounds__(1024) void phaseA(const int* __restrict__ src,
                                               const int* __restrict__ dst,
                                               const float* __restrict__ vals,
                                               int* __restrict__ bcur,
                                               ull* __restrict__ staging) {
    __shared__ int hist[NB];     // counts -> excl bases -> running cursors
    __shared__ int delta[NB];    // global_pos = delta[b] + lds_index
    __shared__ ull recs[CHUNK_A];
    __shared__ int wsum[10];
    const int tid = threadIdx.x;
    const int beg = blockIdx.x * CHUNK_A;

    for (int i = tid; i < NB; i += 1024) hist[i] = 0;
    __syncthreads();
    // pass 1: bucket histogram
    for (int e = tid; e < CHUNK_A; e += 1024)
        atomicAdd(&hist[((unsigned)dst[beg + e]) >> 7], 1);
    __syncthreads();

    // exclusive scan of hist[NB]: 2 entries per thread, wave scan + wave-total scan
    int e0 = 0, e1 = 0, s = 0;
    if (tid < PAIRS) { e0 = hist[2 * tid]; e1 = hist[2 * tid + 1]; s = e0 + e1; }
    int incl = s;
#pragma unroll
    for (int off = 1; off < 64; off <<= 1) {
        int v = __shfl_up(incl, off, 64);
        if ((tid & 63) >= off) incl += v;
    }
    if ((tid & 63) == 63 && (tid >> 6) < 10) wsum[tid >> 6] = incl;
    __syncthreads();
    if (tid == 0) {
        int run = 0;
        for (int w = 0; w < 10; ++w) { int t = wsum[w]; wsum[w] = run; run += t; }
    }
    __syncthreads();
    if (tid < PAIRS) {
        int excl = wsum[tid >> 6] + incl - s;       // base of bucket 2*tid
        int b0 = 2 * tid, b1 = 2 * tid + 1;
        int g0 = e0 ? atomicAdd(&bcur[b0], e0) : 0; // reserve global slots
        int g1 = e1 ? atomicAdd(&bcur[b1], e1) : 0;
        delta[b0] = b0 * CAPB + g0 - excl;
        delta[b1] = b1 * CAPB + g1 - (excl + e0);
        hist[b0] = excl;                            // cursor init
        hist[b1] = excl + e0;
    }
    __syncthreads();

    // pass 2: scatter records into LDS, sorted by bucket
    for (int e = tid; e < CHUNK_A; e += 1024) {
        int d = dst[beg + e];
        unsigned b = ((unsigned)d) >> 7;
        unsigned short hb = __half_as_ushort(__float2half(vals[beg + e]));
        ull rec = ((ull)hb << 36) | ((ull)(unsigned)d << 18)
                | (ull)(unsigned)src[beg + e];
        int lpos = atomicAdd(&hist[b], 1);
        recs[lpos] = rec;
    }
    __syncthreads();

    // sweep: consecutive lanes -> consecutive global addrs within bucket runs
    for (int i = tid; i < CHUNK_A; i += 1024) {
        ull rec = recs[i];
        unsigned d = (unsigned)(rec >> 18) & 0x3FFFFu;
        unsigned b = d >> 7;
        staging[(size_t)(delta[b] + i)] = rec;
    }
}

// ---------- phase B: one block per bucket; LDS-cache records, sort by node ----------
// csr_src holds BYTE offsets into the fp16 table (src * 128)
__global__ __launch_bounds__(256) void phaseB(const ull* __restrict__ staging,
                                              const int* __restrict__ bcur,
                                              unsigned* __restrict__ csr_src,
                                              __half* __restrict__ csr_val,
                                              int* __restrict__ row_ptr,
                                              unsigned short* __restrict__ row_len) {
    __shared__ ull recs[CAPB];       // 48KB
    __shared__ int hist[BKN];
    __shared__ int curs[BKN];
    const int b = blockIdx.x;
    const int cnt = bcur[b];
    const int sbase = b * CAPB;
    for (int i = threadIdx.x; i < BKN; i += 256) hist[i] = 0;
    __syncthreads();
    for (int i = threadIdx.x; i < cnt; i += 256) {
        ull rec = staging[sbase + i];
        recs[i] = rec;
        atomicAdd(&hist[(int)((rec >> 18) & 0x7Fu)], 1);
    }
    __syncthreads();
    // wave 0: exclusive scan of 128 counts; write row_ptr/row_len + cursors
    if (threadIdx.x < 64) {
        int lane = threadIdx.x;
        int carry = 0;
#pragma unroll
        for (int c = 0; c < BKN; c += 64) {
            int x = hist[c + lane];
            int inc = x;
#pragma unroll
            for (int off = 1; off < 64; off <<= 1) {
                int v = __shfl_up(inc, off, 64);
                if (lane >= off) inc += v;
            }
            int excl = carry + inc - x;
            int node = b * BKN + c + lane;
            if (node < N_N) {
                row_ptr[node] = sbase + excl;
                row_len[node] = (unsigned short)x;
            }
            curs[c + lane] = excl;
            carry += __shfl(inc, 63, 64);
        }
    }
    __syncthreads();
    for (int i = threadIdx.x; i < cnt; i += 256) {
        ull rec = recs[i];
        int local = (int)((rec >> 18) & 0x7Fu);
        int pos = sbase + atomicAdd(&curs[local], 1);
        csr_src[pos] = (unsigned)((rec & 0x3FFFFu) << 7);   // byte offset (fp16)
        csr_val[pos] = __ushort_as_half((unsigned short)(rec >> 36));
    }
}

// ---------- fp16-gather inner loop (2 edges/instr, LDS record broadcast) ----------
__device__ __forceinline__ void spmm_row(const char* __restrict__ eb,
                                         const unsigned* __restrict__ csr_src,
                                         const __half* __restrict__ csr_val,
                                         int2 (*recs)[64], int wid, int lane,
                                         int hlf, int col4,
                                         int beg, int end,
                                         float& accx, float& accy) {
    for (int base = beg; base < end; base += 64) {
        int2 rec;
        if (base + lane < end) {
            rec.x = (int)csr_src[base + lane];
            rec.y = __float_as_int(__half2float(csr_val[base + lane]));
        } else {
            rec = make_int2(0, 0);
        }
        recs[wid][lane] = rec;
        int cnt = min(64, end - base);
        int j0 = 0;
        for (; j0 + 32 <= cnt; j0 += 32) {
            unsigned g[16];
            float v[16];
#pragma unroll
            for (int k = 0; k < 16; ++k) {
                int2 r = recs[wid][j0 + 2 * k + hlf];
                v[k] = __int_as_float(r.y);
                g[k] = *(const unsigned*)(eb + (size_t)(unsigned)r.x + col4);
            }
#pragma unroll
            for (int k = 0; k < 16; ++k) {
                __half2 h = *(__half2*)&g[k];
                accx += __low2float(h) * v[k];
                accy += __high2float(h) * v[k];
            }
        }
        for (; j0 < cnt; j0 += 16) {
            unsigned g[8];
            float v[8];
#pragma unroll
            for (int k = 0; k < 8; ++k) {
                int2 r = recs[wid][j0 + 2 * k + hlf];
                v[k] = __int_as_float(r.y);
                g[k] = *(const unsigned*)(eb + (size_t)(unsigned)r.x + col4);
            }
#pragma unroll
            for (int k = 0; k < 8; ++k) {
                __half2 h = *(__half2*)&g[k];
                accx += __low2float(h) * v[k];
                accy += __high2float(h) * v[k];
            }
        }
    }
}

// ---------- fp8-gather inner loop ----------
template<int M>
__device__ __forceinline__ void gather_fma8(const char* __restrict__ eb8,
                                            int2 (*recs)[64], int wid, int j0,
                                            int hlf, int col2,
                                            float& accx, float& accy) {
    unsigned short g[M];
    float v[M];
#pragma unroll
    for (int k = 0; k < M; ++k) {
        int2 r = recs[wid][j0 + 2 * k + hlf];
        v[k] = __int_as_float(r.y);
        g[k] = *(const unsigned short*)(eb8 + (size_t)((unsigned)r.x >> 1) + col2);
    }
#pragma unroll
    for (int k = 0; k < M; ++k) {
        f32x2 f = unpack_fp8(g[k]);
        accx += f[0] * v[k];
        accy += f[1] * v[k];
    }
}

__device__ __forceinline__ void spmm_row8(const char* __restrict__ eb8,
                                          const unsigned* __restrict__ csr_src,
                                          const __half* __restrict__ csr_val,
                                          int2 (*recs)[64], int wid, int lane,
                                          int hlf, int col2,
                                          int beg, int end,
                                          float& accx, float& accy) {
    for (int base = beg; base < end; base += 64) {
        int2 rec;
        if (base + lane < end) {
            rec.x = (int)csr_src[base + lane];
            rec.y = __float_as_int(__half2float(csr_val[base + lane]));
        } else {
            rec = make_int2(0, 0);
        }
        recs[wid][lane] = rec;
        int cnt = min(64, end - base);
        int j0 = 0;
        for (; j0 + 32 <= cnt; j0 += 32)
            gather_fma8<16>(eb8, recs, wid, j0, hlf, col2, accx, accy);
        for (; j0 < cnt; j0 += 16)
            gather_fma8<8>(eb8, recs, wid, j0, hlf, col2, accx, accy);
    }
}

// ---------- layer 1: fp16 gathers from h0; writes h1 (fp16) + b81 (fp8*S1) ----------
__global__ __launch_bounds__(256) void spmm16(const __half2* __restrict__ ecur,
                                              __half2* __restrict__ enext,
                                              unsigned short* __restrict__ out8,
                                              const int* __restrict__ row_ptr,
                                              const unsigned short* __restrict__ row_len,
                                              const unsigned* __restrict__ csr_src,
                                              const __half* __restrict__ csr_val) {
    __shared__ int2 recs[4][64];
    const int wid = threadIdx.x >> 6;
    const int lane = threadIdx.x & 63;
    const int hlf = lane >> 5;
    const int col = lane & 31;
    int row = blockIdx.x * 4 + wid;
    if (row >= N_N) return;
    int beg = row_ptr[row];
    int end = beg + row_len[row];
    float accx = 0.f, accy = 0.f;
    spmm_row((const char*)ecur, csr_src, csr_val, recs, wid, lane, hlf,
             col * 4, beg, end, accx, accy);
    accx += __shfl_xor(accx, 32, 64);
    accy += __shfl_xor(accy, 32, 64);
    if (lane < 32) {
        enext[(size_t)row * 32 + col] = __floats2half2_rn(accx, accy);
        out8[(size_t)row * 32 + col] = pack_fp8(accx * S1_F, accy * S1_F);
    }
}

// ---------- layer 2: fp8 gathers from b81 (e1*S1); writes ONLY b82 (e2*S2) ----------
__global__ __launch_bounds__(256) void spmm8(const unsigned short* __restrict__ e8,
                                             unsigned short* __restrict__ out8,
                                             const int* __restrict__ row_ptr,
                                             const unsigned short* __restrict__ row_len,
                                             const unsigned* __restrict__ csr_src,
                                             const __half* __restrict__ csr_val) {
    __shared__ int2 recs[4][64];
    const int wid = threadIdx.x >> 6;
    const int lane = threadIdx.x & 63;
    const int hlf = lane >> 5;
    const int col = lane & 31;
    int row = blockIdx.x * 4 + wid;
    if (row >= N_N) return;
    int beg = row_ptr[row];
    int end = beg + row_len[row];
    float accx = 0.f, accy = 0.f;   // = e2 * S1
    spmm_row8((const char*)e8, csr_src, csr_val, recs, wid, lane, hlf,
              col * 2, beg, end, accx, accy);
    accx += __shfl_xor(accx, 32, 64);
    accy += __shfl_xor(accy, 32, 64);
    if (lane < 32)
        out8[(size_t)row * 32 + col] =
            pack_fp8(accx * (S2_F / S1_F), accy * (S2_F / S1_F));
}

// ---------- final: per batch slot, e3 by fp8 gather + assemble su/si ----------
// su[slot] = e0(fp32) + e1(h1 fp16) + e2(b82/S2) + e3(gathered, /S2)
__global__ __launch_bounds__(256) void batch_final(const unsigned short* __restrict__ e8,
                                                   const __half2* __restrict__ h1,
                                                   const float2* __restrict__ ue2,
                                                   const float2* __restrict__ ie2,
                                                   const int* __restrict__ users,
                                                   const int* __restrict__ items,
                                                   const int* __restrict__ row_ptr,
                                                   const unsigned short* __restrict__ row_len,
                                                   const unsigned* __restrict__ csr_src,
                                                   const __half* __restrict__ csr_val,
                                                   float2* __restrict__ su2,
                                                   float2* __restrict__ si2) {
    __shared__ int2 recs[4][64];
    const int wid = threadIdx.x >> 6;
    const int lane = threadIdx.x & 63;
    const int hlf = lane >> 5;
    const int col = lane & 31;
    int r = blockIdx.x * 4 + wid;
    if (r >= 2 * B_N) return;
    bool isu = (r < B_N);
    int node = isu ? users[r] : U_N + items[r - B_N];
    int beg = row_ptr[node];
    int end = beg + row_len[node];
    float accx = 0.f, accy = 0.f;   // = e3 * S2
    spmm_row8((const char*)e8, csr_src, csr_val, recs, wid, lane, hlf,
              col * 2, beg, end, accx, accy);
    accx += __shfl_xor(accx, 32, 64);
    accy += __shfl_xor(accy, 32, 64);
    if (lane < 32) {
        float2 e0 = isu ? ue2[(size_t)node * 32 + col]
                        : ie2[(size_t)(node - U_N) * 32 + col];
        __half2 e1 = h1[(size_t)node * 32 + col];
        f32x2 e2 = unpack_fp8(e8[(size_t)node * 32 + col]);
        float2 o;
        o.x = e0.x + __low2float(e1) + (e2[0] + accx) * (1.0f / S2_F);
        o.y = e0.y + __high2float(e1) + (e2[1] + accy) * (1.0f / S2_F);
        if (isu) su2[(size_t)r * 32 + col] = o;
        else     si2[(size_t)(r - B_N) * 32 + col] = o;
    }
}

// ---------- gamma = su.si/16 + 64*(ub+ib) ----------
__global__ __launch_bounds__(256) void gamma_kernel(const float* __restrict__ su,
                                                    const float* __restrict__ si,
                                                    const float* __restrict__ ub,
                                                    const float* __restrict__ ib,
                                                    const int* __restrict__ users,
                                                    const int* __restrict__ items,
                                                    float* __restrict__ out) {
    int b = blockIdx.x * 4 + (threadIdx.x >> 6);
    int lane = threadIdx.x & 63;
    if (b >= B_N) return;
    float p = su[(size_t)b * D_DIM + lane] * si[(size_t)b * D_DIM + lane];
#pragma unroll
    for (int off = 32; off > 0; off >>= 1) p += __shfl_xor(p, off, 64);
    if (lane == 0) {
        float bias = ub[users[b]] + ib[items[b]];
        out[b] = p * (1.0f / 16.0f) + 64.0f * bias;
    }
}

extern "C" void kernel_launch(void* const* d_in, const int* in_sizes, int n_in,
                              void* d_out, int out_size, void* d_ws, size_t ws_size,
                              hipStream_t stream) {
    const float* user_emb  = (const float*)d_in[0];
    const float* item_emb  = (const float*)d_in[1];
    const float* user_bias = (const float*)d_in[2];
    const float* item_bias = (const float*)d_in[3];
    const float* vals      = (const float*)d_in[4];
    const int*   src       = (const int*)d_in[5];
    const int*   dst       = (const int*)d_in[6];
    const int*   users     = (const int*)d_in[7];
    const int*   items     = (const int*)d_in[8];
    float* out = (float*)d_out;

    char* ws = (char*)d_ws;
    size_t off = 0;
    auto alloc = [&](size_t bytes) -> void* {
        void* p = ws + off;
        off += (bytes + 255) & ~(size_t)255;
        return p;
    };
    const size_t SLOTS = (size_t)NB * CAPB;                                   // 7.2M
    __half* h0      = (__half*)alloc(sizeof(__half) * (size_t)N_N * D_DIM);   // 19.2MB
    __half* h1      = (__half*)alloc(sizeof(__half) * (size_t)N_N * D_DIM);   // 19.2MB
    unsigned short* b81 = (unsigned short*)alloc(sizeof(short) * (size_t)N_N * 32); // 9.6MB
    unsigned short* b82 = (unsigned short*)alloc(sizeof(short) * (size_t)N_N * 32); // 9.6MB
    float*  su      = (float*)alloc(sizeof(float) * (size_t)B_N * D_DIM);     // 4.2MB
    float*  si      = (float*)alloc(sizeof(float) * (size_t)B_N * D_DIM);     // 4.2MB
    int*    row_ptr = (int*)alloc(sizeof(int) * N_N);                         // 0.6MB
    unsigned short* row_len = (unsigned short*)alloc(sizeof(short) * N_N);    // 0.3MB
    int*    bcur    = (int*)alloc(sizeof(int) * NB);
    ull*    staging = (ull*)alloc(sizeof(ull) * SLOTS);                       // 57.6MB
    unsigned* csr_src = (unsigned*)alloc(sizeof(unsigned) * SLOTS);           // 28.8MB
    __half* csr_val = (__half*)alloc(sizeof(__half) * SLOTS);                 // 14.4MB

    hipMemsetAsync(bcur, 0, sizeof(int) * NB, stream);

    to_half<<<2048, 256, 0, stream>>>((const float2*)user_emb,
                                      (const float2*)item_emb, (__half2*)h0);
    phaseA<<<1024, 1024, 0, stream>>>(src, dst, vals, bcur, staging);
    phaseB<<<NB, 256, 0, stream>>>(staging, bcur, csr_src, csr_val,
                                   row_ptr, row_len);

    // layer 1: fp16 gathers from h0; write h1 (fp16) + b81 (fp8*S1)
    spmm16<<<(N_N + 3) / 4, 256, 0, stream>>>((const __half2*)h0, (__half2*)h1, b81,
                                              row_ptr, row_len, csr_src, csr_val);
    // layer 2: fp8 gathers from b81; write b82 (fp8*S2) only
    spmm8<<<(N_N + 3) / 4, 256, 0, stream>>>(b81, b82,
                                             row_ptr, row_len, csr_src, csr_val);
    // final: e3 gathers from b82 + assemble su/si = e0+e1+e2+e3 (write, no RMW)
    batch_final<<<(2 * B_N) / 4, 256, 0, stream>>>(b82, (const __half2*)h1,
                                                   (const float2*)user_emb,
                                                   (const float2*)item_emb,
                                                   users, items,
                                                   row_ptr, row_len, csr_src, csr_val,
                                                   (float2*)su, (float2*)si);

    gamma_kernel<<<B_N / 4, 256, 0, stream>>>(su, si, user_bias, item_bias,
                                              users, items, out);
}